// Round 16
// baseline (552.237 us; speedup 1.0000x reference)
//
#include <hip/hip_runtime.h>
#include <math.h>

typedef unsigned int u32;
typedef unsigned short u16;

#define NS 128          // T-1 timesteps
#define A_ 5
#define B_ 128
#define NTH 512
#define BC 16
#define NWG 40          // 5 agents x 8 chunks of 16 rows
#define LOG2PI_F 1.8378770664093453f

// ---- B-fragment packed weight layout (u16 units), per agent ----
// (verified R10-R15, absmax 0)
#define OF_E1 0         // 8 ntiles x 5 ksteps
#define OF_P1 20480
#define OF_D1 40960
#define OF_G  61440     // 24 ntiles x 5
#define OF_E2 122880    // 8 x 4
#define OF_P2 139264
#define OF_D2 155648
#define OF_H  172032    // 4 heads x (1 x 4)
#define OF_DH 180224    // 1 x 4
#define AGE   182272

typedef _Float16 f16x8 __attribute__((ext_vector_type(8)));
typedef float f32x4 __attribute__((ext_vector_type(4)));

__device__ __forceinline__ u16 f2h(float f) { _Float16 h = (_Float16)f; return __builtin_bit_cast(u16, h); }
__device__ __forceinline__ float h2f(u16 u) { return (float)__builtin_bit_cast(_Float16, u); }
__device__ __forceinline__ float frcp_(float x) { return __builtin_amdgcn_rcpf(x); }
__device__ __forceinline__ float fsig_(float x) { return frcp_(1.f + __expf(-x)); }
__device__ __forceinline__ float ftanh_(float x) { return 1.f - 2.f * frcp_(1.f + __expf(2.f * x)); }
__device__ __forceinline__ float fsoftplus_(float x) {
    return fmaxf(x, 0.f) + __logf(1.f + __expf(-fabsf(x)));
}

#define MFMA16(af, bf, acc) __builtin_amdgcn_mfma_f32_16x16x32_f16((af), (bf), (acc), 0, 0, 0)
#define PINF8(v) asm volatile("" : "+v"(v))

#define UST 168
#define AST 168

struct PM {
    const float* __restrict__ y;
    const float* __restrict__ eps;
    const float* __restrict__ eb1; const float* __restrict__ eb2;
    const float* __restrict__ pb1; const float* __restrict__ pb2;
    const float* __restrict__ db1; const float* __restrict__ db2;
    const float* __restrict__ emb; const float* __restrict__ esb;
    const float* __restrict__ pmb; const float* __restrict__ psb;
    const float* __restrict__ dmb; const float* __restrict__ dsb;
    const float* __restrict__ bih; const float* __restrict__ bhh;
    const u16* __restrict__ wq;
    float* __restrict__ partials;
};

// 5-barrier schedule: Φ2{enc1/pri1 + dec-heads(t-1)+NLL} Φ3{enc2/pri2}
// Φ4{heads em/es→z in-wave; pm/ps} Φ6{dec1+GRU+h + KL} Φ7{dec2 + stage(t+1)}
__global__ void __launch_bounds__(NTH, 2) vrnn16(PM p) {
    const int tid = threadIdx.x;
    const int wave = tid >> 6;               // 0..7 = tile group tg
    const int lane = tid & 63;
    const int ln = lane & 15;
    const int lq = lane >> 4;
    const int a = blockIdx.x >> 3;
    const int b0 = (blockIdx.x & 7) * BC;
    const int tg = wave;

    __shared__ __align__(16) u16 GL[61440];
    __shared__ __align__(16) u16 Uf[16 * UST];
    __shared__ __align__(16) u16 aAf[16 * AST], aBf[16 * AST], aCf[16 * AST], aDf[16 * AST];
    __shared__ float mueL[16][17], sdeL[16][17], mupL[16][17], sdpL[16][17];
    __shared__ float xf2[2][16][2];
    __shared__ float dmuL[16][2], dsdL[16][2];
    __shared__ float bE1L[128], bP1L[128], bD1L[128];
    __shared__ float bE2L[128], bP2L[128], bD2L[128];
    __shared__ float bIHL[384], bHHL[384], bHl[64], bDHl[4];
    __shared__ float redW[32];

    const f16x8* __restrict__ W8 = (const f16x8*)p.wq + (size_t)a * (AGE / 8);

    // ---- init ----
    {
        const uint4* gsrc = (const uint4*)(p.wq + (size_t)a * AGE + OF_G);
        uint4* gdst = (uint4*)GL;
        for (int i = tid; i < 61440 / 8; i += NTH) gdst[i] = gsrc[i];
    }
    for (int i = tid; i < 16 * UST; i += NTH) Uf[i] = 0;
    if (tid < 128) {
        bE1L[tid] = p.eb1[a * 128 + tid]; bE2L[tid] = p.eb2[a * 128 + tid];
        bP1L[tid] = p.pb1[a * 128 + tid]; bP2L[tid] = p.pb2[a * 128 + tid];
        bD1L[tid] = p.db1[a * 128 + tid]; bD2L[tid] = p.db2[a * 128 + tid];
    }
    if (tid < 384) { bIHL[tid] = p.bih[a * 384 + tid]; bHHL[tid] = p.bhh[a * 384 + tid]; }
    if (tid < 64) {
        int h = tid >> 4, c = tid & 15;
        bHl[tid] = ((h == 0) ? p.emb : (h == 1) ? p.esb : (h == 2) ? p.pmb : p.psb)[a * 16 + c];
    }
    if (tid < 4) bDHl[tid] = (tid < 2) ? p.dmb[a * 2 + tid] : p.dsb[a * 2 + (tid - 2)];

    // ---- pinned frags: E1/P1/D1 (5 each), E2/P2 (4 each) = 23 frags ----
    f16x8 wE1r[5], wP1r[5], wD1r[5], wE2r[4], wP2r[4];
#pragma unroll
    for (int k = 0; k < 5; ++k) {
        wE1r[k] = W8[OF_E1 / 8 + (tg * 5 + k) * 64 + lane];
        wP1r[k] = W8[OF_P1 / 8 + (tg * 5 + k) * 64 + lane];
        wD1r[k] = W8[OF_D1 / 8 + (tg * 5 + k) * 64 + lane];
    }
#pragma unroll
    for (int k = 0; k < 4; ++k) {
        wE2r[k] = W8[OF_E2 / 8 + (tg * 4 + k) * 64 + lane];
        wP2r[k] = W8[OF_P2 / 8 + (tg * 4 + k) * 64 + lane];
    }
#pragma unroll
    for (int k = 0; k < 5; ++k) { PINF8(wE1r[k]); PINF8(wP1r[k]); PINF8(wD1r[k]); }
#pragma unroll
    for (int k = 0; k < 4; ++k) { PINF8(wE2r[k]); PINF8(wP2r[k]); }

    // ---- loader roles: waves 4-6 ----
    const int tl = tid - 256;
    const int ry = (tl >= 0) ? tl / 10 : 0, jy = (tl >= 0) ? tl - (tl / 10) * 10 : 0; // tl<160
    const int rx = (tl - 160) >> 1, xdx = (tl - 160) & 1;                              // 160<=tl<192

    // ---- prologue: stage t=0, prefetch t=1; eps(0) for wave0 ----
    float ypre = 0.f, xpre = 0.f;
    if (tl >= 0 && tl < 160) {
        Uf[ry * UST + 2 + jy] = f2h(p.y[0 * (B_ * 10) + (b0 + ry) * 10 + jy]);
        ypre = p.y[1 * (B_ * 10) + (b0 + ry) * 10 + jy];
    } else if (tl >= 160 && tl < 192) {
        float v = p.y[1 * (B_ * 10) + (b0 + rx) * 10 + a * 2 + xdx];
        Uf[rx * UST + xdx] = f2h(v); xf2[0][rx][xdx] = v;
        xpre = p.y[2 * (B_ * 10) + (b0 + rx) * 10 + a * 2 + xdx];
    }
    float eps4[4] = {0.f, 0.f, 0.f, 0.f};
    if (wave == 0) {
#pragma unroll
        for (int j = 0; j < 4; ++j)
            eps4[j] = p.eps[(((size_t)0 * A_ + a) * B_ + (b0 + lq * 4 + j)) * 16 + ln];
    }

    float kl_acc = 0.f, nll_acc = 0.f;

    __syncthreads();

#pragma unroll 1
    for (int t = 0; t < NS; ++t) {
        // ---- Φ2: enc1+pri1 (pinned); wave0 also dec-heads(t-1)+NLL ----
        {
            f32x4 accE = {0,0,0,0}, accP = {0,0,0,0};
#pragma unroll
            for (int k = 0; k < 5; ++k) {
                f16x8 af = *(const f16x8*)(Uf + ln * UST + k * 32 + lq * 8);
                accE = MFMA16(af, wE1r[k], accE);
                accP = MFMA16(af, wP1r[k], accP);
            }
            int c = tg * 16 + ln;
            float bE = bE1L[c], bP = bP1L[c];
#pragma unroll
            for (int j = 0; j < 4; ++j) {
                int row = lq * 4 + j;
                aAf[row * AST + c] = f2h(fmaxf(accE[j] + bE, 0.f));
                aCf[row * AST + c] = f2h(fmaxf(accP[j] + bP, 0.f));
            }
        }
        if (wave == 0 && t > 0) {
            f32x4 acc = {0, 0, 0, 0};
#pragma unroll
            for (int k = 0; k < 4; ++k) {
                f16x8 af = *(const f16x8*)(aBf + ln * AST + k * 32 + lq * 8);
                f16x8 bf = W8[OF_DH / 8 + k * 64 + lane];
                acc = MFMA16(af, bf, acc);
            }
            if (ln < 4) {
                float bb = bDHl[ln];
#pragma unroll
                for (int j = 0; j < 4; ++j) {
                    int row = lq * 4 + j;
                    float v = acc[j] + bb;
                    if (ln < 2) dmuL[row][ln] = v;
                    else        dsdL[row][ln - 2] = fsoftplus_(v);
                }
            }
            asm volatile("s_waitcnt lgkmcnt(0)" ::: "memory");
            if (lane < 32) {
                int r = lane >> 1, xd = lane & 1;
                float d = xf2[(t - 1) & 1][r][xd] - dmuL[r][xd];
                float isd = frcp_(dsdL[r][xd]);
                nll_acc += 0.5f * (d * d * isd * isd - 2.f * __logf(isd) + LOG2PI_F);
            }
        }
        __syncthreads();

        // ---- Φ3: enc2+pri2 (pinned); waves 0-1 pre-issue H frag loads ----
        f16x8 bh0, bh1, bh2, bh3, bh4, bh5, bh6, bh7;
        if (wave < 2) {
            int hb = wave * 2;   // wave0: heads 0,1 (em,es); wave1: heads 2,3 (pm,ps)
            bh0 = W8[OF_H / 8 + (hb + 0) * 256 + 0 * 64 + lane];
            bh1 = W8[OF_H / 8 + (hb + 0) * 256 + 1 * 64 + lane];
            bh2 = W8[OF_H / 8 + (hb + 0) * 256 + 2 * 64 + lane];
            bh3 = W8[OF_H / 8 + (hb + 0) * 256 + 3 * 64 + lane];
            bh4 = W8[OF_H / 8 + (hb + 1) * 256 + 0 * 64 + lane];
            bh5 = W8[OF_H / 8 + (hb + 1) * 256 + 1 * 64 + lane];
            bh6 = W8[OF_H / 8 + (hb + 1) * 256 + 2 * 64 + lane];
            bh7 = W8[OF_H / 8 + (hb + 1) * 256 + 3 * 64 + lane];
        }
        {
            f32x4 accE = {0,0,0,0}, accP = {0,0,0,0};
#pragma unroll
            for (int k = 0; k < 4; ++k) {
                f16x8 a1 = *(const f16x8*)(aAf + ln * AST + k * 32 + lq * 8);
                f16x8 a2 = *(const f16x8*)(aCf + ln * AST + k * 32 + lq * 8);
                accE = MFMA16(a1, wE2r[k], accE);
                accP = MFMA16(a2, wP2r[k], accP);
            }
            int c = tg * 16 + ln;
            float bE = bE2L[c], bP = bP2L[c];
#pragma unroll
            for (int j = 0; j < 4; ++j) {
                int row = lq * 4 + j;
                aBf[row * AST + c] = f2h(fmaxf(accE[j] + bE, 0.f));
                aDf[row * AST + c] = f2h(fmaxf(accP[j] + bP, 0.f));
            }
        }
        __syncthreads();

        // ---- Φ4: heads. wave0: em,es -> stats + z (in-wave); wave1: pm,ps ----
        if (wave < 2) {
            const u16* src = (wave == 0) ? aBf : aDf;
            f32x4 aM = {0,0,0,0}, aS = {0,0,0,0};
            {
                f16x8 af0 = *(const f16x8*)(src + ln * AST + 0 * 32 + lq * 8);
                f16x8 af1 = *(const f16x8*)(src + ln * AST + 1 * 32 + lq * 8);
                f16x8 af2 = *(const f16x8*)(src + ln * AST + 2 * 32 + lq * 8);
                f16x8 af3 = *(const f16x8*)(src + ln * AST + 3 * 32 + lq * 8);
                aM = MFMA16(af0, bh0, aM); aM = MFMA16(af1, bh1, aM);
                aM = MFMA16(af2, bh2, aM); aM = MFMA16(af3, bh3, aM);
                aS = MFMA16(af0, bh4, aS); aS = MFMA16(af1, bh5, aS);
                aS = MFMA16(af2, bh6, aS); aS = MFMA16(af3, bh7, aS);
            }
            if (wave == 0) {
                float bbm = bHl[0 * 16 + ln], bbs = bHl[1 * 16 + ln];
#pragma unroll
                for (int j = 0; j < 4; ++j) {
                    int row = lq * 4 + j;
                    float em = aM[j] + bbm;
                    float es = fsoftplus_(aS[j] + bbs);
                    mueL[row][ln] = em; sdeL[row][ln] = es;
                    Uf[row * UST + 12 + ln] = f2h(fmaf(eps4[j], es, em));
                }
                // prefetch eps for t+1
                int tn = (t + 1 < NS) ? t + 1 : t;
#pragma unroll
                for (int j = 0; j < 4; ++j)
                    eps4[j] = p.eps[(((size_t)tn * A_ + a) * B_ + (b0 + lq * 4 + j)) * 16 + ln];
            } else {
                float bbm = bHl[2 * 16 + ln], bbs = bHl[3 * 16 + ln];
#pragma unroll
                for (int j = 0; j < 4; ++j) {
                    int row = lq * 4 + j;
                    mupL[row][ln] = aM[j] + bbm;
                    sdpL[row][ln] = fsoftplus_(aS[j] + bbs);
                }
            }
        }
        __syncthreads();

        // ---- Φ6: dec1 (pinned) + GRU (GL) + h write; all waves also KL ----
        {
            f32x4 aO = {0,0,0,0}, g0 = {0,0,0,0}, g1 = {0,0,0,0};
            f32x4 g2i = {0,0,0,0}, g2h = {0,0,0,0};
#pragma unroll
            for (int k = 0; k < 5; ++k) {
                f16x8 af = *(const f16x8*)(Uf + ln * UST + k * 32 + lq * 8);
                aO = MFMA16(af, wD1r[k], aO);
                f16x8 b0 = *(const f16x8*)(GL + ((0 + tg) * 5 + k) * 512 + lane * 8);
                g0 = MFMA16(af, b0, g0);
                f16x8 b1 = *(const f16x8*)(GL + ((8 + tg) * 5 + k) * 512 + lane * 8);
                g1 = MFMA16(af, b1, g1);
                f16x8 b2 = *(const f16x8*)(GL + ((16 + tg) * 5 + k) * 512 + lane * 8);
                if (k == 0) g2i = MFMA16(af, b2, g2i);
                else        g2h = MFMA16(af, b2, g2h);
            }
            // KL for 32 (row,ze) pairs per wave (stats from Φ4)
            if (lane < 32) {
                int pr = wave * 32 + lane;
                int r = pr >> 4, z2 = pr & 15;
                float em = mueL[r][z2], es = sdeL[r][z2];
                float pm = mupL[r][z2], ps = sdpL[r][z2];
                float dm = em - pm;
                float ips = frcp_(ps);
                kl_acc += 0.5f * (2.f * __logf(ps * frcp_(es)) + (es * es + dm * dm) * ips * ips - 1.f);
            }
            int c = tg * 16 + ln;
            float bD = bD1L[c];
            float br = bIHL[c] + bHHL[c];
            float bz = bIHL[128 + c] + bHHL[128 + c];
            float bgi = bIHL[256 + c], bgh = bHHL[256 + c];
#pragma unroll
            for (int j = 0; j < 4; ++j) {
                int row = lq * 4 + j;
                aAf[row * AST + c] = f2h(fmaxf(aO[j] + bD, 0.f));
                float rr = fsig_(g0[j] + br);
                float zz = fsig_(g1[j] + bz);
                float nn = ftanh_(fmaf(rr, g2h[j] + bgh, g2i[j] + bgi));
                float hold = h2f(Uf[row * UST + 32 + c]);
                Uf[row * UST + 32 + c] = f2h(fmaf(zz, hold - nn, nn));
            }
        }
        __syncthreads();

        // ---- Φ7: dec2 (streamed) -> aBf; loaders stage t+1 ----
        {
            f16x8 bd2[4];
#pragma unroll
            for (int k = 0; k < 4; ++k)
                bd2[k] = W8[OF_D2 / 8 + (tg * 4 + k) * 64 + lane];
            f32x4 acc = {0,0,0,0};
#pragma unroll
            for (int k = 0; k < 4; ++k) {
                f16x8 af = *(const f16x8*)(aAf + ln * AST + k * 32 + lq * 8);
                acc = MFMA16(af, bd2[k], acc);
            }
            int c = tg * 16 + ln;
            float bE = bD2L[c];
#pragma unroll
            for (int j = 0; j < 4; ++j)
                aBf[(lq * 4 + j) * AST + c] = f2h(fmaxf(acc[j] + bE, 0.f));
        }
        {
            // stage inputs for step t+1 (y(t+1), x(t+1)=y[t+2])
            int yctx = (t + 2 < NS) ? t + 2 : NS - 1;       // prefetch y for step t+2
            int yxn  = (t + 3 <= NS) ? t + 3 : NS;          // prefetch x for step t+2
            if (tl >= 0 && tl < 160) {
                Uf[ry * UST + 2 + jy] = f2h(ypre);
                ypre = p.y[yctx * (B_ * 10) + (b0 + ry) * 10 + jy];
            } else if (tl >= 160 && tl < 192) {
                Uf[rx * UST + xdx] = f2h(xpre);
                xf2[(t + 1) & 1][rx][xdx] = xpre;
                xpre = p.y[yxn * (B_ * 10) + (b0 + rx) * 10 + a * 2 + xdx];
            }
        }
        __syncthreads();
    }

    // ---- epilogue: dec-heads + NLL for step NS-1 ----
    if (wave == 0) {
        f32x4 acc = {0, 0, 0, 0};
#pragma unroll
        for (int k = 0; k < 4; ++k) {
            f16x8 af = *(const f16x8*)(aBf + ln * AST + k * 32 + lq * 8);
            f16x8 bf = W8[OF_DH / 8 + k * 64 + lane];
            acc = MFMA16(af, bf, acc);
        }
        if (ln < 4) {
            float bb = bDHl[ln];
#pragma unroll
            for (int j = 0; j < 4; ++j) {
                int row = lq * 4 + j;
                float v = acc[j] + bb;
                if (ln < 2) dmuL[row][ln] = v;
                else        dsdL[row][ln - 2] = fsoftplus_(v);
            }
        }
        asm volatile("s_waitcnt lgkmcnt(0)" ::: "memory");
        if (lane < 32) {
            int r = lane >> 1, xd = lane & 1;
            float d = xf2[(NS - 1) & 1][r][xd] - dmuL[r][xd];
            float isd = frcp_(dsdL[r][xd]);
            nll_acc += 0.5f * (d * d * isd * isd - 2.f * __logf(isd) + LOG2PI_F);
        }
    }

    // ---- block reduction ----
    __syncthreads();
    {
        float k = kl_acc, n = nll_acc;
        k += __shfl_xor(k, 1);  n += __shfl_xor(n, 1);
        k += __shfl_xor(k, 2);  n += __shfl_xor(n, 2);
        k += __shfl_xor(k, 4);  n += __shfl_xor(n, 4);
        k += __shfl_xor(k, 8);  n += __shfl_xor(n, 8);
        k += __shfl_xor(k, 16); n += __shfl_xor(n, 16);
        k += __shfl_xor(k, 32); n += __shfl_xor(n, 32);
        if (lane == 0) { redW[wave] = k; redW[16 + wave] = n; }
    }
    __syncthreads();
    if (tid == 0) {
        float s = 0.f, s2 = 0.f;
#pragma unroll
        for (int i = 0; i < 8; ++i) { s += redW[i]; s2 += redW[16 + i]; }
        p.partials[blockIdx.x] = s;
        p.partials[NWG + blockIdx.x] = s2;
    }
}

// ---------------- prep: pack weights into B-fragment order ----------------
struct PrepP {
    const float* eW1; const float* pW1; const float* dW1;
    const float* wih; const float* whh;
    const float* eW2; const float* pW2; const float* dW2;
    const float* hW[4];
    const float* dmW; const float* dsW;
    u16* dst;
};

__global__ void prep4(PrepP pp) {
    const int jNT[12]  = {8,8,8,24, 8,8,8, 1,1,1,1, 1};
    const int jKST[12] = {5,5,5,5, 4,4,4, 4,4,4,4, 4};
    const int jOFS[12] = {OF_E1,OF_P1,OF_D1,OF_G, OF_E2,OF_P2,OF_D2,
                          OF_H,OF_H+2048,OF_H+4096,OF_H+6144, OF_DH};
    const int jkt[3]   = {140,138,154};

    int job = blockIdx.y;
    int nt = jNT[job], kst = jKST[job];
    int per_agent = nt * kst * 512;
    int total = A_ * per_agent;
    int idx = blockIdx.x * 256 + threadIdx.x;
    if (idx >= total) return;
    int a = idx / per_agent;
    int rem = idx - a * per_agent;
    int slot = rem >> 9;
    int within = rem & 511;
    int lane = within >> 3, j = within & 7;
    int ntile = slot / kst, kstep = slot - ntile * kst;
    int k = kstep * 32 + (lane >> 4) * 8 + j;
    int n = ntile * 16 + (lane & 15);

    float val = 0.f;
    if (job < 3) {
        int sk = -1;
        if (job == 0)      sk = (k < 12) ? k : (k >= 32 ? k - 20 : -1);
        else if (job == 1) sk = (k >= 2 && k < 12) ? k - 2 : (k >= 32 ? k - 22 : -1);
        else               sk = (k >= 2 && k < 28) ? k - 2 : (k >= 32 ? k - 6 : -1);
        const float* s = (job == 0) ? pp.eW1 : (job == 1) ? pp.pW1 : pp.dW1;
        if (sk >= 0) val = s[((size_t)a * jkt[job] + sk) * 128 + n];
    } else if (job == 3) {
        if (k < 2)                  val = pp.wih[((size_t)a * 384 + n) * 18 + k];
        else if (k >= 12 && k < 28) val = pp.wih[((size_t)a * 384 + n) * 18 + (k - 10)];
        else if (k >= 32)           val = pp.whh[((size_t)a * 384 + n) * 128 + (k - 32)];
    } else if (job < 7) {
        const float* s = (job == 4) ? pp.eW2 : (job == 5) ? pp.pW2 : pp.dW2;
        val = s[((size_t)a * 128 + k) * 128 + n];
    } else if (job < 11) {
        val = pp.hW[job - 7][((size_t)a * 128 + k) * 16 + n];
    } else {
        if (n < 2)      val = pp.dmW[((size_t)a * 128 + k) * 2 + n];
        else if (n < 4) val = pp.dsW[((size_t)a * 128 + k) * 2 + (n - 2)];
    }
    pp.dst[(size_t)a * AGE + jOFS[job] + rem] = f2h(val);
}

__global__ void finish_kernel(const float* __restrict__ partials, float* __restrict__ out) {
    int tid = threadIdx.x;   // 64 threads
    float k = (tid < NWG) ? partials[tid] : 0.f;
    float n = (tid < NWG) ? partials[NWG + tid] : 0.f;
    k += __shfl_xor(k, 1);  n += __shfl_xor(n, 1);
    k += __shfl_xor(k, 2);  n += __shfl_xor(n, 2);
    k += __shfl_xor(k, 4);  n += __shfl_xor(n, 4);
    k += __shfl_xor(k, 8);  n += __shfl_xor(n, 8);
    k += __shfl_xor(k, 16); n += __shfl_xor(n, 16);
    k += __shfl_xor(k, 32); n += __shfl_xor(n, 32);
    if (tid == 0) { out[0] = k; out[1] = n; }
}

extern "C" void kernel_launch(void* const* d_in, const int* in_sizes, int n_in,
                              void* d_out, int out_size, void* d_ws, size_t ws_size,
                              hipStream_t stream) {
    float* partials = (float*)d_ws;
    u16* wq = (u16*)((char*)d_ws + 4096);

    PrepP pp;
    pp.eW1 = (const float*)d_in[2];
    pp.pW1 = (const float*)d_in[10];
    pp.dW1 = (const float*)d_in[18];
    pp.wih = (const float*)d_in[26];
    pp.whh = (const float*)d_in[27];
    pp.eW2 = (const float*)d_in[4];
    pp.pW2 = (const float*)d_in[12];
    pp.dW2 = (const float*)d_in[20];
    pp.hW[0] = (const float*)d_in[6];
    pp.hW[1] = (const float*)d_in[8];
    pp.hW[2] = (const float*)d_in[14];
    pp.hW[3] = (const float*)d_in[16];
    pp.dmW = (const float*)d_in[22];
    pp.dsW = (const float*)d_in[24];
    pp.dst = wq;
    prep4<<<dim3(1200, 12), 256, 0, stream>>>(pp);

    PM p;
    p.y   = (const float*)d_in[0];
    p.eps = (const float*)d_in[1];
    p.eb1 = (const float*)d_in[3];  p.eb2 = (const float*)d_in[5];
    p.emb = (const float*)d_in[7];  p.esb = (const float*)d_in[9];
    p.pb1 = (const float*)d_in[11]; p.pb2 = (const float*)d_in[13];
    p.pmb = (const float*)d_in[15]; p.psb = (const float*)d_in[17];
    p.db1 = (const float*)d_in[19]; p.db2 = (const float*)d_in[21];
    p.dmb = (const float*)d_in[23]; p.dsb = (const float*)d_in[25];
    p.bih = (const float*)d_in[28]; p.bhh = (const float*)d_in[29];
    p.wq = wq;
    p.partials = partials;

    vrnn16<<<NWG, NTH, 0, stream>>>(p);
    finish_kernel<<<1, 64, 0, stream>>>(partials, (float*)d_out);
}

// Round 17
// 487.460 us; speedup vs baseline: 1.1329x; 1.1329x over previous
//
#include <hip/hip_runtime.h>
#include <math.h>

typedef unsigned int u32;
typedef unsigned short u16;

#define NS 128          // T-1 timesteps
#define A_ 5
#define B_ 128
#define NTH 512
#define BC 16
#define NWG 40          // 5 agents x 8 chunks of 16 rows
#define LOG2PI_F 1.8378770664093453f

// ---- B-fragment packed weight layout (u16 units), per agent ----
// (verified R10-R16, absmax 0)
#define OF_E1 0         // 8 ntiles x 5 ksteps
#define OF_P1 20480
#define OF_D1 40960
#define OF_G  61440     // 24 ntiles x 5
#define OF_E2 122880    // 8 x 4
#define OF_P2 139264
#define OF_D2 155648
#define OF_H  172032    // 4 heads x (1 x 4)
#define OF_DH 180224    // 1 x 4
#define AGE   182272

typedef _Float16 f16x8 __attribute__((ext_vector_type(8)));
typedef float f32x4 __attribute__((ext_vector_type(4)));

__device__ __forceinline__ u16 f2h(float f) { _Float16 h = (_Float16)f; return __builtin_bit_cast(u16, h); }
__device__ __forceinline__ float h2f(u16 u) { return (float)__builtin_bit_cast(_Float16, u); }
__device__ __forceinline__ float frcp_(float x) { return __builtin_amdgcn_rcpf(x); }
__device__ __forceinline__ float fsig_(float x) { return frcp_(1.f + __expf(-x)); }
__device__ __forceinline__ float ftanh_(float x) { return 1.f - 2.f * frcp_(1.f + __expf(2.f * x)); }
__device__ __forceinline__ float fsoftplus_(float x) {
    return fmaxf(x, 0.f) + __logf(1.f + __expf(-fabsf(x)));
}

#define MFMA16(af, bf, acc) __builtin_amdgcn_mfma_f32_16x16x32_f16((af), (bf), (acc), 0, 0, 0)
#define PINF8(v) asm volatile("" : "+v"(v))

#define UST 168   // Uf stride: 84*ln mod 32 -> full bank spread
#define AST 152   // act stride: 76*ln mod 32 = 12*ln -> 2-way max

struct PM {
    const float* __restrict__ y;
    const float* __restrict__ eps;
    const float* __restrict__ eb1; const float* __restrict__ eb2;
    const float* __restrict__ pb1; const float* __restrict__ pb2;
    const float* __restrict__ db1; const float* __restrict__ db2;
    const float* __restrict__ emb; const float* __restrict__ esb;
    const float* __restrict__ pmb; const float* __restrict__ psb;
    const float* __restrict__ dmb; const float* __restrict__ dsb;
    const float* __restrict__ bih; const float* __restrict__ bhh;
    const u16* __restrict__ wq;
    float* __restrict__ partials;
};

// R15 base + all in-loop global ops consolidated into P7 (one vmcnt drain
// per step instead of three); DH weights in LDS so P1 is pure-LDS.
__global__ void __launch_bounds__(NTH, 2) vrnn17(PM p) {
    const int tid = threadIdx.x;
    const int wave = tid >> 6;               // 0..7 = tile group tg
    const int lane = tid & 63;
    const int ln = lane & 15;
    const int lq = lane >> 4;
    const int a = blockIdx.x >> 3;
    const int b0 = (blockIdx.x & 7) * BC;
    const int tg = wave;

    __shared__ __align__(16) u16 GL[61440];          // GRU B-frags, 120KB
    __shared__ __align__(16) u16 DHL[2048];          // dec-head B-frags, 4KB
    __shared__ __align__(16) u16 Uf[16 * UST];
    __shared__ __align__(16) u16 aAf[16 * AST], aBf[16 * AST], aCf[16 * AST], aDf[16 * AST];
    __shared__ float mueL[16][16], sdeL[16][16], mupL[16][16], sdpL[16][16];
    __shared__ float xf2[2][16][2];
    __shared__ float dmuL[16][2], dsdL[16][2];
    __shared__ float bE1L[128], bP1L[128], bD1L[128];
    __shared__ float bE2L[128], bP2L[128], bD2L[128];
    __shared__ float bIHL[384], bHHL[384], bHl[64], bDHl[4];
    __shared__ float redW[32];

    const f16x8* __restrict__ W8 = (const f16x8*)p.wq + (size_t)a * (AGE / 8);

    // ---- init: G + DH to LDS, biases, zero U ----
    {
        const uint4* gsrc = (const uint4*)(p.wq + (size_t)a * AGE + OF_G);
        uint4* gdst = (uint4*)GL;
        for (int i = tid; i < 61440 / 8; i += NTH) gdst[i] = gsrc[i];
        const uint4* dsrc = (const uint4*)(p.wq + (size_t)a * AGE + OF_DH);
        uint4* ddst = (uint4*)DHL;
        if (tid < 256) ddst[tid] = dsrc[tid];
    }
    for (int i = tid; i < 16 * UST; i += NTH) Uf[i] = 0;
    if (tid < 128) {
        bE1L[tid] = p.eb1[a * 128 + tid]; bE2L[tid] = p.eb2[a * 128 + tid];
        bP1L[tid] = p.pb1[a * 128 + tid]; bP2L[tid] = p.pb2[a * 128 + tid];
        bD1L[tid] = p.db1[a * 128 + tid]; bD2L[tid] = p.db2[a * 128 + tid];
    }
    if (tid < 384) { bIHL[tid] = p.bih[a * 384 + tid]; bHHL[tid] = p.bhh[a * 384 + tid]; }
    if (tid < 64) {
        int h = tid >> 4, c = tid & 15;
        bHl[tid] = ((h == 0) ? p.emb : (h == 1) ? p.esb : (h == 2) ? p.pmb : p.psb)[a * 16 + c];
    }
    if (tid < 4) bDHl[tid] = (tid < 2) ? p.dmb[a * 2 + tid] : p.dsb[a * 2 + (tid - 2)];

    // ---- pinned frags: E1/P1/D1 (5), E2/P2 (4), H (4) = 27 frags ----
    f16x8 wE1r[5], wP1r[5], wD1r[5], wE2r[4], wP2r[4], wHr[4];
#pragma unroll
    for (int k = 0; k < 5; ++k) {
        wE1r[k] = W8[OF_E1 / 8 + (tg * 5 + k) * 64 + lane];
        wP1r[k] = W8[OF_P1 / 8 + (tg * 5 + k) * 64 + lane];
        wD1r[k] = W8[OF_D1 / 8 + (tg * 5 + k) * 64 + lane];
    }
#pragma unroll
    for (int k = 0; k < 4; ++k) {
        wE2r[k] = W8[OF_E2 / 8 + (tg * 4 + k) * 64 + lane];
        wP2r[k] = W8[OF_P2 / 8 + (tg * 4 + k) * 64 + lane];
        wHr[k]  = W8[OF_H / 8 + (tg & 3) * 256 + k * 64 + lane];
    }
#pragma unroll
    for (int k = 0; k < 5; ++k) { PINF8(wE1r[k]); PINF8(wP1r[k]); PINF8(wD1r[k]); }
#pragma unroll
    for (int k = 0; k < 4; ++k) { PINF8(wE2r[k]); PINF8(wP2r[k]); PINF8(wHr[k]); }

    // ---- loader roles: waves 4-6 ----
    const int tl = tid - 256;
    const int ry = (tl >= 0) ? tl / 10 : 0, jy = (tl >= 0) ? tl - (tl / 10) * 10 : 0; // tl<160
    const int rx = (tl - 160) >> 1, xdx = (tl - 160) & 1;                              // 160<=tl<192
    const int re = tid >> 4, ze = tid & 15;                                            // tid<256 (P5)

    // ---- prologue: stage t=0 y/x, prefetch t=1; eps(0) ----
    float ypre = 0.f, xpre = 0.f, epre = 0.f;
    if (tl >= 0 && tl < 160) {
        Uf[ry * UST + 2 + jy] = f2h(p.y[0 * (B_ * 10) + (b0 + ry) * 10 + jy]);
        ypre = p.y[1 * (B_ * 10) + (b0 + ry) * 10 + jy];
    } else if (tl >= 160 && tl < 192) {
        float v = p.y[1 * (B_ * 10) + (b0 + rx) * 10 + a * 2 + xdx];
        Uf[rx * UST + xdx] = f2h(v); xf2[0][rx][xdx] = v;
        xpre = p.y[2 * (B_ * 10) + (b0 + rx) * 10 + a * 2 + xdx];
    }
    if (tid < 256) epre = p.eps[(((size_t)0 * A_ + a) * B_ + (b0 + re)) * 16 + ze];

    float kl_acc = 0.f, nll_acc = 0.f;

    __syncthreads();

#pragma unroll 1
    for (int t = 0; t < NS; ++t) {
        // ---- P1: wave0 dec-heads(t-1)+NLL (pure LDS; DH frags from DHL) ----
        if (wave == 0 && t > 0) {
            f32x4 acc = {0, 0, 0, 0};
#pragma unroll
            for (int k = 0; k < 4; ++k) {
                f16x8 af = *(const f16x8*)(aBf + ln * AST + k * 32 + lq * 8);
                f16x8 bf = *(const f16x8*)(DHL + k * 512 + lane * 8);
                acc = MFMA16(af, bf, acc);
            }
            if (ln < 4) {
                float bb = bDHl[ln];
#pragma unroll
                for (int j = 0; j < 4; ++j) {
                    int row = lq * 4 + j;
                    float v = acc[j] + bb;
                    if (ln < 2) dmuL[row][ln] = v;
                    else        dsdL[row][ln - 2] = fsoftplus_(v);
                }
            }
            asm volatile("s_waitcnt lgkmcnt(0)" ::: "memory");
            if (lane < 32) {
                int r = lane >> 1, xd = lane & 1;
                float d = xf2[(t - 1) & 1][r][xd] - dmuL[r][xd];
                float isd = frcp_(dsdL[r][xd]);
                nll_acc += 0.5f * (d * d * isd * isd - 2.f * __logf(isd) + LOG2PI_F);
            }
        }
        __syncthreads();

        // ---- P2: enc1 (pinned E1) + pri1 (pinned P1) ----
        {
            f32x4 accE = {0,0,0,0}, accP = {0,0,0,0};
#pragma unroll
            for (int k = 0; k < 5; ++k) {
                f16x8 af = *(const f16x8*)(Uf + ln * UST + k * 32 + lq * 8);
                accE = MFMA16(af, wE1r[k], accE);
                accP = MFMA16(af, wP1r[k], accP);
            }
            int c = tg * 16 + ln;
            float bE = bE1L[c], bP = bP1L[c];
#pragma unroll
            for (int j = 0; j < 4; ++j) {
                int row = lq * 4 + j;
                aAf[row * AST + c] = f2h(fmaxf(accE[j] + bE, 0.f));
                aCf[row * AST + c] = f2h(fmaxf(accP[j] + bP, 0.f));
            }
        }
        __syncthreads();

        // ---- P3: enc2 (pinned E2) + pri2 (pinned P2) ----
        {
            f32x4 accE = {0,0,0,0}, accP = {0,0,0,0};
#pragma unroll
            for (int k = 0; k < 4; ++k) {
                f16x8 a1 = *(const f16x8*)(aAf + ln * AST + k * 32 + lq * 8);
                f16x8 a2 = *(const f16x8*)(aCf + ln * AST + k * 32 + lq * 8);
                accE = MFMA16(a1, wE2r[k], accE);
                accP = MFMA16(a2, wP2r[k], accP);
            }
            int c = tg * 16 + ln;
            float bE = bE2L[c], bP = bP2L[c];
#pragma unroll
            for (int j = 0; j < 4; ++j) {
                int row = lq * 4 + j;
                aBf[row * AST + c] = f2h(fmaxf(accE[j] + bE, 0.f));
                aDf[row * AST + c] = f2h(fmaxf(accP[j] + bP, 0.f));
            }
        }
        __syncthreads();

        // ---- P4: 4 gaussian heads (waves 0-3; pinned H) ----
        if (wave < 4) {
            const u16* src = (wave < 2) ? aBf : aDf;
            f32x4 acc = {0,0,0,0};
#pragma unroll
            for (int k = 0; k < 4; ++k) {
                f16x8 af = *(const f16x8*)(src + ln * AST + k * 32 + lq * 8);
                acc = MFMA16(af, wHr[k], acc);
            }
            float bb = bHl[wave * 16 + ln];
#pragma unroll
            for (int j = 0; j < 4; ++j) {
                int row = lq * 4 + j;
                float v = acc[j] + bb;
                if (wave == 0)      mueL[row][ln] = v;
                else if (wave == 1) sdeL[row][ln] = fsoftplus_(v);
                else if (wave == 2) mupL[row][ln] = v;
                else                sdpL[row][ln] = fsoftplus_(v);
            }
        }
        __syncthreads();

        // ---- P5: z sample + KL (256 threads; eps from reg) ----
        if (tid < 256) {
            float em = mueL[re][ze], es = sdeL[re][ze], pm = mupL[re][ze], ps = sdpL[re][ze];
            float zv = fmaf(epre, es, em);
            Uf[re * UST + 12 + ze] = f2h(zv);
            float dm = em - pm;
            float ips = frcp_(ps);
            kl_acc += 0.5f * (2.f * __logf(ps * frcp_(es)) + (es * es + dm * dm) * ips * ips - 1.f);
        }
        __syncthreads();

        // ---- P6: dec1 (pinned D1) + GRU gates (GL) + h write ----
        {
            f32x4 aO = {0,0,0,0}, g0 = {0,0,0,0}, g1 = {0,0,0,0};
            f32x4 g2i = {0,0,0,0}, g2h = {0,0,0,0};
#pragma unroll
            for (int k = 0; k < 5; ++k) {
                f16x8 af = *(const f16x8*)(Uf + ln * UST + k * 32 + lq * 8);
                aO = MFMA16(af, wD1r[k], aO);
                f16x8 b0 = *(const f16x8*)(GL + ((0 + tg) * 5 + k) * 512 + lane * 8);
                g0 = MFMA16(af, b0, g0);
                f16x8 b1 = *(const f16x8*)(GL + ((8 + tg) * 5 + k) * 512 + lane * 8);
                g1 = MFMA16(af, b1, g1);
                f16x8 b2 = *(const f16x8*)(GL + ((16 + tg) * 5 + k) * 512 + lane * 8);
                if (k == 0) g2i = MFMA16(af, b2, g2i);
                else        g2h = MFMA16(af, b2, g2h);
            }
            int c = tg * 16 + ln;
            float bD = bD1L[c];
            float br = bIHL[c] + bHHL[c];
            float bz = bIHL[128 + c] + bHHL[128 + c];
            float bgi = bIHL[256 + c], bgh = bHHL[256 + c];
#pragma unroll
            for (int j = 0; j < 4; ++j) {
                int row = lq * 4 + j;
                aAf[row * AST + c] = f2h(fmaxf(aO[j] + bD, 0.f));
                float rr = fsig_(g0[j] + br);
                float zz = fsig_(g1[j] + bz);
                float nn = ftanh_(fmaf(rr, g2h[j] + bgh, g2i[j] + bgi));
                float hold = h2f(Uf[row * UST + 32 + c]);
                Uf[row * UST + 32 + c] = f2h(fmaf(zz, hold - nn, nn));
            }
        }
        __syncthreads();

        // ---- P7: dec2 (D2 streamed) + ALL global staging for t+1 ----
        {
            f16x8 bd2[4];
#pragma unroll
            for (int k = 0; k < 4; ++k)
                bd2[k] = W8[OF_D2 / 8 + (tg * 4 + k) * 64 + lane];
            f32x4 acc = {0,0,0,0};
#pragma unroll
            for (int k = 0; k < 4; ++k) {
                f16x8 af = *(const f16x8*)(aAf + ln * AST + k * 32 + lq * 8);
                acc = MFMA16(af, bd2[k], acc);
            }
            int c = tg * 16 + ln;
            float bE = bD2L[c];
#pragma unroll
            for (int j = 0; j < 4; ++j)
                aBf[(lq * 4 + j) * AST + c] = f2h(fmaxf(acc[j] + bE, 0.f));
        }
        {
            // commit y(t+1)/x(t+1) into Uf (P6 already consumed step-t U);
            // prefetch y(t+2)/x(t+2); eps(t+1). Only phase with global loads.
            int ynx = (t + 2 <= NS) ? t + 2 : NS;           // y index for next prefetch
            int xnx = (t + 3 <= NS) ? t + 3 : NS;
            if (tl >= 0 && tl < 160) {
                Uf[ry * UST + 2 + jy] = f2h(ypre);
                ypre = p.y[ynx * (B_ * 10) + (b0 + ry) * 10 + jy];
            } else if (tl >= 160 && tl < 192) {
                Uf[rx * UST + xdx] = f2h(xpre);
                xf2[(t + 1) & 1][rx][xdx] = xpre;
                xpre = p.y[xnx * (B_ * 10) + (b0 + rx) * 10 + a * 2 + xdx];
            }
            if (tid < 256) {
                int tn = (t + 1 < NS) ? t + 1 : t;
                epre = p.eps[(((size_t)tn * A_ + a) * B_ + (b0 + re)) * 16 + ze];
            }
        }
        __syncthreads();
    }

    // ---- epilogue: dec-heads + NLL for step NS-1 ----
    if (wave == 0) {
        f32x4 acc = {0, 0, 0, 0};
#pragma unroll
        for (int k = 0; k < 4; ++k) {
            f16x8 af = *(const f16x8*)(aBf + ln * AST + k * 32 + lq * 8);
            f16x8 bf = *(const f16x8*)(DHL + k * 512 + lane * 8);
            acc = MFMA16(af, bf, acc);
        }
        if (ln < 4) {
            float bb = bDHl[ln];
#pragma unroll
            for (int j = 0; j < 4; ++j) {
                int row = lq * 4 + j;
                float v = acc[j] + bb;
                if (ln < 2) dmuL[row][ln] = v;
                else        dsdL[row][ln - 2] = fsoftplus_(v);
            }
        }
        asm volatile("s_waitcnt lgkmcnt(0)" ::: "memory");
        if (lane < 32) {
            int r = lane >> 1, xd = lane & 1;
            float d = xf2[(NS - 1) & 1][r][xd] - dmuL[r][xd];
            float isd = frcp_(dsdL[r][xd]);
            nll_acc += 0.5f * (d * d * isd * isd - 2.f * __logf(isd) + LOG2PI_F);
        }
    }

    // ---- block reduction ----
    __syncthreads();
    {
        float k = kl_acc, n = nll_acc;
        k += __shfl_xor(k, 1);  n += __shfl_xor(n, 1);
        k += __shfl_xor(k, 2);  n += __shfl_xor(n, 2);
        k += __shfl_xor(k, 4);  n += __shfl_xor(n, 4);
        k += __shfl_xor(k, 8);  n += __shfl_xor(n, 8);
        k += __shfl_xor(k, 16); n += __shfl_xor(n, 16);
        k += __shfl_xor(k, 32); n += __shfl_xor(n, 32);
        if (lane == 0) { redW[wave] = k; redW[16 + wave] = n; }
    }
    __syncthreads();
    if (tid == 0) {
        float s = 0.f, s2 = 0.f;
#pragma unroll
        for (int i = 0; i < 8; ++i) { s += redW[i]; s2 += redW[16 + i]; }
        p.partials[blockIdx.x] = s;
        p.partials[NWG + blockIdx.x] = s2;
    }
}

// ---------------- prep: pack weights into B-fragment order ----------------
struct PrepP {
    const float* eW1; const float* pW1; const float* dW1;
    const float* wih; const float* whh;
    const float* eW2; const float* pW2; const float* dW2;
    const float* hW[4];
    const float* dmW; const float* dsW;
    u16* dst;
};

__global__ void prep4(PrepP pp) {
    const int jNT[12]  = {8,8,8,24, 8,8,8, 1,1,1,1, 1};
    const int jKST[12] = {5,5,5,5, 4,4,4, 4,4,4,4, 4};
    const int jOFS[12] = {OF_E1,OF_P1,OF_D1,OF_G, OF_E2,OF_P2,OF_D2,
                          OF_H,OF_H+2048,OF_H+4096,OF_H+6144, OF_DH};
    const int jkt[3]   = {140,138,154};

    int job = blockIdx.y;
    int nt = jNT[job], kst = jKST[job];
    int per_agent = nt * kst * 512;
    int total = A_ * per_agent;
    int idx = blockIdx.x * 256 + threadIdx.x;
    if (idx >= total) return;
    int a = idx / per_agent;
    int rem = idx - a * per_agent;
    int slot = rem >> 9;
    int within = rem & 511;
    int lane = within >> 3, j = within & 7;
    int ntile = slot / kst, kstep = slot - ntile * kst;
    int k = kstep * 32 + (lane >> 4) * 8 + j;
    int n = ntile * 16 + (lane & 15);

    float val = 0.f;
    if (job < 3) {
        int sk = -1;
        if (job == 0)      sk = (k < 12) ? k : (k >= 32 ? k - 20 : -1);
        else if (job == 1) sk = (k >= 2 && k < 12) ? k - 2 : (k >= 32 ? k - 22 : -1);
        else               sk = (k >= 2 && k < 28) ? k - 2 : (k >= 32 ? k - 6 : -1);
        const float* s = (job == 0) ? pp.eW1 : (job == 1) ? pp.pW1 : pp.dW1;
        if (sk >= 0) val = s[((size_t)a * jkt[job] + sk) * 128 + n];
    } else if (job == 3) {
        if (k < 2)                  val = pp.wih[((size_t)a * 384 + n) * 18 + k];
        else if (k >= 12 && k < 28) val = pp.wih[((size_t)a * 384 + n) * 18 + (k - 10)];
        else if (k >= 32)           val = pp.whh[((size_t)a * 384 + n) * 128 + (k - 32)];
    } else if (job < 7) {
        const float* s = (job == 4) ? pp.eW2 : (job == 5) ? pp.pW2 : pp.dW2;
        val = s[((size_t)a * 128 + k) * 128 + n];
    } else if (job < 11) {
        val = pp.hW[job - 7][((size_t)a * 128 + k) * 16 + n];
    } else {
        if (n < 2)      val = pp.dmW[((size_t)a * 128 + k) * 2 + n];
        else if (n < 4) val = pp.dsW[((size_t)a * 128 + k) * 2 + (n - 2)];
    }
    pp.dst[(size_t)a * AGE + jOFS[job] + rem] = f2h(val);
}

__global__ void finish_kernel(const float* __restrict__ partials, float* __restrict__ out) {
    int tid = threadIdx.x;   // 64 threads
    float k = (tid < NWG) ? partials[tid] : 0.f;
    float n = (tid < NWG) ? partials[NWG + tid] : 0.f;
    k += __shfl_xor(k, 1);  n += __shfl_xor(n, 1);
    k += __shfl_xor(k, 2);  n += __shfl_xor(n, 2);
    k += __shfl_xor(k, 4);  n += __shfl_xor(n, 4);
    k += __shfl_xor(k, 8);  n += __shfl_xor(n, 8);
    k += __shfl_xor(k, 16); n += __shfl_xor(n, 16);
    k += __shfl_xor(k, 32); n += __shfl_xor(n, 32);
    if (tid == 0) { out[0] = k; out[1] = n; }
}

extern "C" void kernel_launch(void* const* d_in, const int* in_sizes, int n_in,
                              void* d_out, int out_size, void* d_ws, size_t ws_size,
                              hipStream_t stream) {
    float* partials = (float*)d_ws;
    u16* wq = (u16*)((char*)d_ws + 4096);

    PrepP pp;
    pp.eW1 = (const float*)d_in[2];
    pp.pW1 = (const float*)d_in[10];
    pp.dW1 = (const float*)d_in[18];
    pp.wih = (const float*)d_in[26];
    pp.whh = (const float*)d_in[27];
    pp.eW2 = (const float*)d_in[4];
    pp.pW2 = (const float*)d_in[12];
    pp.dW2 = (const float*)d_in[20];
    pp.hW[0] = (const float*)d_in[6];
    pp.hW[1] = (const float*)d_in[8];
    pp.hW[2] = (const float*)d_in[14];
    pp.hW[3] = (const float*)d_in[16];
    pp.dmW = (const float*)d_in[22];
    pp.dsW = (const float*)d_in[24];
    pp.dst = wq;
    prep4<<<dim3(1200, 12), 256, 0, stream>>>(pp);

    PM p;
    p.y   = (const float*)d_in[0];
    p.eps = (const float*)d_in[1];
    p.eb1 = (const float*)d_in[3];  p.eb2 = (const float*)d_in[5];
    p.emb = (const float*)d_in[7];  p.esb = (const float*)d_in[9];
    p.pb1 = (const float*)d_in[11]; p.pb2 = (const float*)d_in[13];
    p.pmb = (const float*)d_in[15]; p.psb = (const float*)d_in[17];
    p.db1 = (const float*)d_in[19]; p.db2 = (const float*)d_in[21];
    p.dmb = (const float*)d_in[23]; p.dsb = (const float*)d_in[25];
    p.bih = (const float*)d_in[28]; p.bhh = (const float*)d_in[29];
    p.wq = wq;
    p.partials = partials;

    vrnn17<<<NWG, NTH, 0, stream>>>(p);
    finish_kernel<<<1, 64, 0, stream>>>(partials, (float*)d_out);
}